// Round 1
// baseline (1516.380 us; speedup 1.0000x reference)
//
#include <hip/hip_runtime.h>
#include <math.h>

// TVB MPR simulation + BOLD, single-workgroup latency-optimized design.
//
// N=128 regions, NH=128 max lag, 1000 Heun steps, fused BOLD chain.
// One block, 256 threads (2 threads/region), r-history ring in LDS.
//
// Key identity: coupling for d2 at step s == coupling for d1 at step s+1
// (both read hist[s+1-lags]); so one gather per step, carried over.

namespace {
constexpr int NREG  = 128;
constexpr int RING  = 256;          // power-of-2 ring >= NH+STEPS window
constexpr int NSTEP = 1000;         // NCHUNK * STEPS

__device__ __forceinline__ float pow3125(float v) {
    // v^3.125 = v^3 * v^(1/8)
    float s1 = sqrtf(v);
    float s2 = sqrtf(s1);
    float s3 = sqrtf(s2);
    return v * v * v * s3;
}
} // namespace

__launch_bounds__(256, 1)
__global__ void tvb_kernel(const float* __restrict__ region_pars,  // (128,1)
                           const float* __restrict__ Wt,           // (128,128,1)
                           const float* __restrict__ g,            // (1,)
                           const float* __restrict__ stimulus,     // (100,1)
                           const float* __restrict__ noise,        // (100,10,128,2)
                           const float* __restrict__ initial_cond, // (128,2)
                           const int*   __restrict__ lags,         // (128,128)
                           float* __restrict__ out)                // rv(1000,128,2) ++ bold(128)
{
    // hist[j * RING + slot]: r-value of region j at time slot (slot = (T+256)&255)
    __shared__ float hist[NREG * RING];   // 128 KB

    const int tid = (int)threadIdx.x;
    const int i   = tid >> 1;     // region this thread serves
    const int h   = tid & 1;      // which half of the j-range
    const int jb  = h << 6;       // 0 or 64
    const int jbR = jb * RING;    // LDS word offset of this thread's j-block

    // ---- preload W row-half and lags row-half into registers ----
    float w[64];
    int   lg[64];
#pragma unroll
    for (int k = 0; k < 64; ++k) {
        w[k]  = Wt[i * NREG + jb + k];
        lg[k] = lags[i * NREG + jb + k];
    }

    const float eta = region_pars[i];
    const float g0  = g[0];
    const float r0  = initial_cond[2 * i];
    float xr = r0;                       // current state (abs time T)
    float xV = initial_cond[2 * i + 1];

    // ---- init ring: every slot of region i = r0 (history times <= 0) ----
    {
        float4 v4 = make_float4(r0, r0, r0, r0);
        float4* dst = reinterpret_cast<float4*>(&hist[i * RING + (h << 7)]);
#pragma unroll
        for (int m = 0; m < 32; ++m) dst[m] = v4;
    }
    __syncthreads();

    // ---- constants (match reference f32 rounding) ----
    constexpr float ONE_PI = (float)(1.0 / 3.14159265358979323846); // DELTA/(pi*TAU)
    constexpr float PI_F   = (float)3.14159265358979323846;         // pi*TAU
    constexpr float RTS    = (float)(1.0 / 0.65);
    constexpr float RTF    = (float)(1.0 / 0.41);
    constexpr float RTO    = (float)(1.0 / 0.98);
    constexpr float K1     = (float)(4.3 * 40.3 * 0.4 * 0.04);
    constexpr float K2     = (float)(0.5 * 25.0 * 0.4 * 0.04);
    constexpr float L06    = -0.7369655941662062f;                  // log2(0.6)
    const float DWS = 0.01f * sqrtf(0.1f);                          // SIGMA*sqrt(DT)

    // gather coupling for time T = sIdx+1: sum_j W[i,j]*hist[(sIdx+1-lag)&255][j]
    auto gather = [&](int sIdx) -> float {
        const int C = sIdx + 257;        // slot index before masking
        float a0 = 0.f, a1 = 0.f, a2 = 0.f, a3 = 0.f;
#pragma unroll
        for (int k = 0; k < 64; k += 4) {
            int s0 = (C - lg[k])     & 255;
            int s1 = (C - lg[k + 1]) & 255;
            int s2 = (C - lg[k + 2]) & 255;
            int s3 = (C - lg[k + 3]) & 255;
            a0 = fmaf(w[k],     hist[jbR + (k)     * RING + s0], a0);
            a1 = fmaf(w[k + 1], hist[jbR + (k + 1) * RING + s1], a1);
            a2 = fmaf(w[k + 2], hist[jbR + (k + 2) * RING + s2], a2);
            a3 = fmaf(w[k + 3], hist[jbR + (k + 3) * RING + s3], a3);
        }
        float acc = (a0 + a1) + (a2 + a3);
        acc += __shfl_xor(acc, 1);       // combine the two halves of the pair
        return acc;
    };

    // BOLD state (ones init)
    float bs = 1.f, bf = 1.f, bv = 1.f, bq = 1.f;

    // initial coupling c(T=0): all history = r0
    float c_cur = gather(-1);

    for (int s = 0; s < NSTEP; ++s) {
        // issue global loads early so latency hides under the gather
        const float2 nz = *reinterpret_cast<const float2*>(&noise[(size_t)(s * NREG + i) * 2]);
        const float stim_c = stimulus[s / 10];
        const float stim_i = (i == 0) ? stim_c : 0.f;

        // coupling for d2 this step (== d1 coupling of next step)
        const float c_next = gather(s);

        const float dw_r = DWS * nz.x;
        const float dw_V = DWS * nz.y;

        // ---- MPR Heun step ----
        const float I1  = g0 * c_cur + stim_i;
        const float dr1 = ONE_PI + (2.0f * xr) * xV;
        const float p1  = PI_F * xr;
        const float dV1 = ((xV * xV + eta) + 15.0f * xr + I1) - p1 * p1;

        const float xir = fmaxf((xr + 0.1f * dr1) + dw_r, 0.f);
        const float xiV = (xV + 0.1f * dV1) + dw_V;

        const float I2  = g0 * c_next + stim_i;
        const float dr2 = ONE_PI + (2.0f * xir) * xiV;
        const float p2  = PI_F * xir;
        const float dV2 = ((xiV * xiV + eta) + 15.0f * xir + I2) - p2 * p2;

        const float nxr = fmaxf((xr + 0.05f * (dr1 + dr2)) + dw_r, 0.f);
        const float nxV = (xV + 0.05f * (dV1 + dV2)) + dw_V;

        if (h == 0) {
            // write new r into ring at slot (s+1+256)&255
            hist[i * RING + ((s + 257) & 255)] = nxr;
            // rv output
            *reinterpret_cast<float2*>(&out[(size_t)(s * NREG + i) * 2]) =
                make_float2(nxr, nxV);
        }

        // ---- fused BOLD Heun step (x = nxr); redundant in both half-lanes ----
        {
            const float x = nxr;
            const float pv1 = pow3125(bv);
            const float e1  = exp2f(L06 / bf);
            const float d1s = x - RTS * bs - RTF * (bf - 1.f);
            const float d1f = bs;
            const float d1v = RTO * (bf - pv1);
            const float d1q = RTO * (bf * (1.f - e1) / 0.4f - pv1 * bq / bv);

            const float s2v = bs + 0.01f * d1s;
            const float f2v = bf + 0.01f * d1f;
            const float v2v = bv + 0.01f * d1v;
            const float q2v = bq + 0.01f * d1q;

            const float pv2 = pow3125(v2v);
            const float e2  = exp2f(L06 / f2v);
            const float d2s = x - RTS * s2v - RTF * (f2v - 1.f);
            const float d2f = s2v;
            const float d2v = RTO * (f2v - pv2);
            const float d2q = RTO * (f2v * (1.f - e2) / 0.4f - pv2 * q2v / v2v);

            bs += 0.005f * (d1s + d2s);
            bf += 0.005f * (d1f + d2f);
            bv += 0.005f * (d1v + d2v);
            bq += 0.005f * (d1q + d2q);
        }

        xr = nxr;
        xV = nxV;
        c_cur = c_next;

        __syncthreads();   // make hist[s+1] visible before next step's gather
    }

    if (h == 0) {
        const float bold = 4.0f * (K1 * (1.f - bq) + K2 * (1.f - bq / bv) + 0.5f * (1.f - bv));
        out[(size_t)NSTEP * NREG * 2 + i] = bold;
    }
}

extern "C" void kernel_launch(void* const* d_in, const int* in_sizes, int n_in,
                              void* d_out, int out_size, void* d_ws, size_t ws_size,
                              hipStream_t stream) {
    const float* region_pars  = (const float*)d_in[0];
    const float* Wt           = (const float*)d_in[1];
    const float* g            = (const float*)d_in[2];
    const float* stimulus     = (const float*)d_in[3];
    const float* noise        = (const float*)d_in[4];
    const float* initial_cond = (const float*)d_in[5];
    const int*   lags         = (const int*)d_in[6];
    // d_in[7] = ix_lag_from: always tile(arange(N)) -> implicit in our layout

    tvb_kernel<<<dim3(1), dim3(256), 0, stream>>>(
        region_pars, Wt, g, stimulus, noise, initial_cond, lags, (float*)d_out);
}

// Round 2
// 1408.492 us; speedup vs baseline: 1.0766x; 1.0766x over previous
//
#include <hip/hip_runtime.h>
#include <math.h>

// TVB MPR simulation + BOLD, single-workgroup latency-optimized design, v2.
//
// v2 change: conflict-free LDS gather.
//  - History ring TRANSPOSED: hist[slot*128 + j] -> bank = j % 32 (data-indep).
//  - Per-thread j-order bank-spread: at unrolled instr k, lane l reads
//    j with j%32 == (k/2 + l%32)%32 -> every bank hit exactly 2x (free).
//  - Address = (sC9 + Q[k]) & 0x1FFFC, Q[k] = ((256-lag)<<9)|(j<<2): the AND
//    does the mod-256 ring wrap, OR-as-ADD folds j (slot part 512B-aligned).
//
// Key identity kept from v1: coupling for d2 at step s == coupling for d1 at
// step s+1, so one gather per step.

namespace {
constexpr int NREG  = 128;
constexpr int RING  = 256;          // power-of-2 ring >= NH+STEPS window
constexpr int NSTEP = 1000;         // NCHUNK * STEPS

__device__ __forceinline__ float pow3125(float v) {
    // v^3.125 = v^3 * v^(1/8)
    float s1 = sqrtf(v);
    float s2 = sqrtf(s1);
    float s3 = sqrtf(s2);
    return v * v * v * s3;
}
} // namespace

__launch_bounds__(256, 1)
__global__ void tvb_kernel(const float* __restrict__ region_pars,  // (128,1)
                           const float* __restrict__ Wt,           // (128,128,1)
                           const float* __restrict__ g,            // (1,)
                           const float* __restrict__ stimulus,     // (100,1)
                           const float* __restrict__ noise,        // (100,10,128,2)
                           const float* __restrict__ initial_cond, // (128,2)
                           const int*   __restrict__ lags,         // (128,128)
                           float* __restrict__ out)                // rv(1000,128,2) ++ bold(128)
{
    // hist[slot * NREG + j]: r-value of region j at time slot ((T+256)&255)
    __shared__ float hist[RING * NREG];   // 128 KB

    const int tid  = (int)threadIdx.x;
    const int i    = tid >> 1;     // region this thread serves
    const int h    = tid & 1;      // which half of the j-range
    const int lane = tid & 63;
    const int rot  = lane & 31;
    const int jb   = h << 6;       // 0 or 64

    // ---- preload W row-half + lag row-half in bank-spread order ----
    // position k = 2c+d  ->  j = jb + 32*d + ((c + rot) & 31)
    // => at instr k, the wave's 64 lanes cover each bank (j%32) exactly twice.
    float w[64];
    int   Q[64];
#pragma unroll
    for (int k = 0; k < 64; ++k) {
        const int c = k >> 1;
        const int d = k & 1;
        const int j = jb + (d << 5) + ((c + rot) & 31);
        w[k] = Wt[i * NREG + j];
        const int lg = lags[i * NREG + j];
        Q[k] = ((256 - lg) << 9) | (j << 2);
    }

    const float eta = region_pars[i];
    const float g0  = g[0];
    const float r0  = initial_cond[2 * i];
    float xr = r0;                       // current state (abs time T)
    float xV = initial_cond[2 * i + 1];

    // ---- init ring: every slot's row = r0 vector ----
    if (h == 0) hist[255 * NREG + i] = r0;
    __syncthreads();
    {
        const int slot = tid;            // 0..255
        if (slot != 255) {
            float4*       dst = reinterpret_cast<float4*>(&hist[slot * NREG]);
            const float4* src = reinterpret_cast<const float4*>(&hist[255 * NREG]);
#pragma unroll
            for (int m = 0; m < 32; ++m) dst[m] = src[m];
        }
    }
    __syncthreads();

    // ---- constants (match reference f32 rounding) ----
    constexpr float ONE_PI = (float)(1.0 / 3.14159265358979323846); // DELTA/(pi*TAU)
    constexpr float PI_F   = (float)3.14159265358979323846;         // pi*TAU
    constexpr float RTS    = (float)(1.0 / 0.65);
    constexpr float RTF    = (float)(1.0 / 0.41);
    constexpr float RTO    = (float)(1.0 / 0.98);
    constexpr float K1     = (float)(4.3 * 40.3 * 0.4 * 0.04);
    constexpr float K2     = (float)(0.5 * 25.0 * 0.4 * 0.04);
    constexpr float L06    = -0.7369655941662062f;                  // log2(0.6)
    const float DWS = 0.01f * sqrtf(0.1f);                          // SIGMA*sqrt(DT)

    // gather coupling at ring time C: sum_j W[i,j]*hist[((C-lag)&255)*128 + j]
    auto gather = [&](int C) -> float {
        const int sC9 = (C & 255) << 9;  // scalar per step
        float a0 = 0.f, a1 = 0.f, a2 = 0.f, a3 = 0.f;
#pragma unroll
        for (int k = 0; k < 64; k += 4) {
            const int t0 = (sC9 + Q[k])     & 0x1FFFC;
            const int t1 = (sC9 + Q[k + 1]) & 0x1FFFC;
            const int t2 = (sC9 + Q[k + 2]) & 0x1FFFC;
            const int t3 = (sC9 + Q[k + 3]) & 0x1FFFC;
            a0 = fmaf(w[k],     *(const float*)((const char*)hist + t0), a0);
            a1 = fmaf(w[k + 1], *(const float*)((const char*)hist + t1), a1);
            a2 = fmaf(w[k + 2], *(const float*)((const char*)hist + t2), a2);
            a3 = fmaf(w[k + 3], *(const float*)((const char*)hist + t3), a3);
        }
        float acc = (a0 + a1) + (a2 + a3);
        acc += __shfl_xor(acc, 1);       // combine the two halves of the pair
        return acc;
    };

    // BOLD state (ones init)
    float bs = 1.f, bf = 1.f, bv = 1.f, bq = 1.f;

    // initial coupling c(T=0): all history = r0  (ring time C = 256)
    float c_cur = gather(256);

    // noise prefetch (one step ahead)
    float2 nz = *reinterpret_cast<const float2*>(&noise[(size_t)i * 2]);

    for (int s = 0; s < NSTEP; ++s) {
        // prefetch next step's noise; latency hides under this step's gather
        const int sn = (s + 1 < NSTEP) ? (s + 1) : s;
        const float2 nz_next =
            *reinterpret_cast<const float2*>(&noise[(size_t)(sn * NREG + i) * 2]);
        const float stim_c = stimulus[s / 10];
        const float stim_i = (i == 0) ? stim_c : 0.f;

        // coupling for d2 this step (== d1 coupling of next step); time s+1
        const float c_next = gather(s + 257);

        const float dw_r = DWS * nz.x;
        const float dw_V = DWS * nz.y;

        // ---- MPR Heun step ----
        const float I1  = g0 * c_cur + stim_i;
        const float dr1 = ONE_PI + (2.0f * xr) * xV;
        const float p1  = PI_F * xr;
        const float dV1 = ((xV * xV + eta) + 15.0f * xr + I1) - p1 * p1;

        const float xir = fmaxf((xr + 0.1f * dr1) + dw_r, 0.f);
        const float xiV = (xV + 0.1f * dV1) + dw_V;

        const float I2  = g0 * c_next + stim_i;
        const float dr2 = ONE_PI + (2.0f * xir) * xiV;
        const float p2  = PI_F * xir;
        const float dV2 = ((xiV * xiV + eta) + 15.0f * xir + I2) - p2 * p2;

        const float nxr = fmaxf((xr + 0.05f * (dr1 + dr2)) + dw_r, 0.f);
        const float nxV = (xV + 0.05f * (dV1 + dV2)) + dw_V;

        if (h == 0) {
            // write new r into transposed ring at slot (s+257)&255
            hist[(((s + 257) & 255) << 7) + i] = nxr;
            // rv output
            *reinterpret_cast<float2*>(&out[(size_t)(s * NREG + i) * 2]) =
                make_float2(nxr, nxV);
        }

        // ---- fused BOLD Heun step (x = nxr); redundant in both half-lanes ----
        {
            const float x = nxr;
            const float pv1 = pow3125(bv);
            const float e1  = exp2f(L06 / bf);
            const float d1s = x - RTS * bs - RTF * (bf - 1.f);
            const float d1f = bs;
            const float d1v = RTO * (bf - pv1);
            const float d1q = RTO * (bf * (1.f - e1) / 0.4f - pv1 * bq / bv);

            const float s2v = bs + 0.01f * d1s;
            const float f2v = bf + 0.01f * d1f;
            const float v2v = bv + 0.01f * d1v;
            const float q2v = bq + 0.01f * d1q;

            const float pv2 = pow3125(v2v);
            const float e2  = exp2f(L06 / f2v);
            const float d2s = x - RTS * s2v - RTF * (f2v - 1.f);
            const float d2f = s2v;
            const float d2v = RTO * (f2v - pv2);
            const float d2q = RTO * (f2v * (1.f - e2) / 0.4f - pv2 * q2v / v2v);

            bs += 0.005f * (d1s + d2s);
            bf += 0.005f * (d1f + d2f);
            bv += 0.005f * (d1v + d2v);
            bq += 0.005f * (d1q + d2q);
        }

        xr = nxr;
        xV = nxV;
        c_cur = c_next;
        nz = nz_next;

        __syncthreads();   // make hist[s+1] visible before next step's gather
    }

    if (h == 0) {
        const float bold = 4.0f * (K1 * (1.f - bq) + K2 * (1.f - bq / bv) + 0.5f * (1.f - bv));
        out[(size_t)NSTEP * NREG * 2 + i] = bold;
    }
}

extern "C" void kernel_launch(void* const* d_in, const int* in_sizes, int n_in,
                              void* d_out, int out_size, void* d_ws, size_t ws_size,
                              hipStream_t stream) {
    const float* region_pars  = (const float*)d_in[0];
    const float* Wt           = (const float*)d_in[1];
    const float* g            = (const float*)d_in[2];
    const float* stimulus     = (const float*)d_in[3];
    const float* noise        = (const float*)d_in[4];
    const float* initial_cond = (const float*)d_in[5];
    const int*   lags         = (const int*)d_in[6];
    // d_in[7] = ix_lag_from: always tile(arange(N)) -> implicit in our layout

    tvb_kernel<<<dim3(1), dim3(256), 0, stream>>>(
        region_pars, Wt, g, stimulus, noise, initial_cond, lags, (float*)d_out);
}

// Round 3
// 713.261 us; speedup vs baseline: 2.1260x; 1.9747x over previous
//
#include <hip/hip_runtime.h>
#include <math.h>

// TVB MPR simulation + BOLD, v3: role-specialized waves for latency hiding.
//
// 768 threads = 12 waves (3/SIMD):
//   waves 0-7 : coupling gather (4 threads/region, 32 terms each, bank-spread)
//   waves 8-9 : MPR Heun update (1 thread/region, holds state in regs)
//   waves 10-11: BOLD Heun chain, one step behind (reads r from LDS ring)
//
// Ring: hist[slot*128 + j], slot = time & 255. Bank = j%32 (data-independent).
// One gather per step (d2 coupling at s == d1 coupling at s+1).

namespace {
constexpr int NREG  = 128;
constexpr int NSTEP = 1000;

__device__ __forceinline__ float fsqrt_raw(float x){ float r; asm("v_sqrt_f32 %0, %1" : "=v"(r) : "v"(x)); return r; }
__device__ __forceinline__ float frcp_raw (float x){ float r; asm("v_rcp_f32 %0, %1" : "=v"(r) : "v"(x)); return r; }
__device__ __forceinline__ float fexp2_raw(float x){ float r; asm("v_exp_f32 %0, %1" : "=v"(r) : "v"(x)); return r; }

__device__ __forceinline__ float pow3125(float v) {
    // v^3.125 = v^3 * v^(1/8)
    float s1 = fsqrt_raw(v);
    float s2 = fsqrt_raw(s1);
    float s3 = fsqrt_raw(s2);
    return v * v * v * s3;
}

// quad-perm DPP butterfly adds (full-rate VALU, no LDS pipe)
__device__ __forceinline__ float dpp_add_xor1(float x){
    int y = __builtin_amdgcn_mov_dpp(__float_as_int(x), 0xB1, 0xF, 0xF, true); // [1,0,3,2]
    return x + __int_as_float(y);
}
__device__ __forceinline__ float dpp_add_xor2(float x){
    int y = __builtin_amdgcn_mov_dpp(__float_as_int(x), 0x4E, 0xF, 0xF, true); // [2,3,0,1]
    return x + __int_as_float(y);
}
} // namespace

__launch_bounds__(768, 1)
__global__ void tvb_kernel(const float* __restrict__ region_pars,  // (128,1)
                           const float* __restrict__ Wt,           // (128,128,1)
                           const float* __restrict__ g,            // (1,)
                           const float* __restrict__ stimulus,     // (100,1)
                           const float* __restrict__ noise,        // (100,10,128,2)
                           const float* __restrict__ initial_cond, // (128,2)
                           const int*   __restrict__ lags,         // (128,128)
                           float* __restrict__ out)                // rv(1000,128,2) ++ bold(128)
{
    __shared__ float hist[256 * NREG];   // 128 KB ring: hist[slot*128 + j]
    __shared__ float cbuf[NREG];         // per-step coupling sums

    const int tid = (int)threadIdx.x;
    const int wid = tid >> 6;

    // ---- constants ----
    constexpr float ONE_PI = (float)(1.0 / 3.14159265358979323846);
    constexpr float PI_F   = (float)3.14159265358979323846;
    constexpr float RTS    = (float)(1.0 / 0.65);
    constexpr float RTF    = (float)(1.0 / 0.41);
    constexpr float RTO    = (float)(1.0 / 0.98);
    constexpr float K1     = (float)(4.3 * 40.3 * 0.4 * 0.04);
    constexpr float K2     = (float)(0.5 * 25.0 * 0.4 * 0.04);
    constexpr float L06    = -0.7369655941662062f;                  // log2(0.6)
    const float DWS = 0.01f * sqrtf(0.1f);

    // ---- init ring with r0 (history times <= 0) ----
    if (tid < NREG) cbuf[tid] = initial_cond[2 * tid];
    __syncthreads();
    for (int e = tid; e < 256 * NREG; e += 768) hist[e] = cbuf[e & 127];
    __syncthreads();

    // ================= role setup =================
    // gather waves
    float w[32];
    int   Q[32];
    if (wid < 8) {
        const int i    = tid >> 2;            // region
        const int h    = tid & 3;             // quarter of j-range
        const int lane = tid & 63;
        const int rot  = (lane >> 2) + ((lane & 3) << 3);
#pragma unroll
        for (int k = 0; k < 32; ++k) {
            const int j = (h << 5) | ((k + rot) & 31);
            w[k] = Wt[i * NREG + j];
            const int lg = lags[i * NREG + j];
            Q[k] = ((256 - lg) << 9) | (j << 2);
        }
    }

    // MPR waves' state
    float xr = 0.f, xV = 0.f, eta = 0.f, g0 = 0.f, c_cur = 0.f;
    float2 nz = make_float2(0.f, 0.f);
    const int i2 = tid - 512;   // region for MPR waves (valid when wid==8,9)
    const int i3 = tid - 640;   // region for BOLD waves (valid when wid==10,11)

    // BOLD state
    float bs = 1.f, bf = 1.f, bv = 1.f, bq = 1.f;

    // gather for c(0): ring time 0, reads slots (0 - lag) & 255 in [128,255]
    auto do_gather = [&](int T) {
        const int sC9 = (T & 255) << 9;
        float a0 = 0.f, a1 = 0.f, a2 = 0.f, a3 = 0.f;
#pragma unroll
        for (int k = 0; k < 32; k += 4) {
            const int t0 = (sC9 + Q[k])     & 0x1FFFC;
            const int t1 = (sC9 + Q[k + 1]) & 0x1FFFC;
            const int t2 = (sC9 + Q[k + 2]) & 0x1FFFC;
            const int t3 = (sC9 + Q[k + 3]) & 0x1FFFC;
            a0 = fmaf(w[k],     *(const float*)((const char*)hist + t0), a0);
            a1 = fmaf(w[k + 1], *(const float*)((const char*)hist + t1), a1);
            a2 = fmaf(w[k + 2], *(const float*)((const char*)hist + t2), a2);
            a3 = fmaf(w[k + 3], *(const float*)((const char*)hist + t3), a3);
        }
        float a = (a0 + a1) + (a2 + a3);
        a = dpp_add_xor1(a);
        a = dpp_add_xor2(a);
        if ((tid & 3) == 0) cbuf[tid >> 2] = a;
    };

    // ---- prologue: c(0) into cbuf, MPR state load ----
    if (wid < 8) do_gather(0);
    __syncthreads();
    if (wid == 8 || wid == 9) {
        c_cur = cbuf[i2];
        eta   = region_pars[i2];
        g0    = g[0];
        xr    = initial_cond[2 * i2];
        xV    = initial_cond[2 * i2 + 1];
        nz    = *reinterpret_cast<const float2*>(&noise[(size_t)i2 * 2]);
    }
    __syncthreads();   // protect cbuf before loop's first overwrite

    float2 nz_next = make_float2(0.f, 0.f);
    float  stim_i  = 0.f;
    float  xb      = 0.f;

    // BOLD single Heun step (captures state by ref)
    auto bstep = [&](float x) {
        const float pv1 = pow3125(bv);
        const float e1  = fexp2_raw(L06 * frcp_raw(bf));
        const float d1s = x - RTS * bs - RTF * (bf - 1.f);
        const float d1f = bs;
        const float d1v = RTO * (bf - pv1);
        const float d1q = RTO * (bf * (1.f - e1) * 2.5f - pv1 * bq * frcp_raw(bv));

        const float s2v = bs + 0.01f * d1s;
        const float f2v = bf + 0.01f * d1f;
        const float v2v = bv + 0.01f * d1v;
        const float q2v = bq + 0.01f * d1q;

        const float pv2 = pow3125(v2v);
        const float e2  = fexp2_raw(L06 * frcp_raw(f2v));
        const float d2s = x - RTS * s2v - RTF * (f2v - 1.f);
        const float d2f = s2v;
        const float d2v = RTO * (f2v - pv2);
        const float d2q = RTO * (f2v * (1.f - e2) * 2.5f - pv2 * q2v * frcp_raw(v2v));

        bs += 0.005f * (d1s + d2s);
        bf += 0.005f * (d1f + d2f);
        bv += 0.005f * (d1v + d2v);
        bq += 0.005f * (d1q + d2q);
    };

    for (int s = 0; s < NSTEP; ++s) {
        // ---------- phase A ----------
        if (wid < 8) {
            do_gather(s + 1);                 // coupling c(s+1) -> cbuf
        } else if (wid < 10) {
            const int sn = (s < NSTEP - 1) ? s + 1 : NSTEP - 1;
            nz_next = *reinterpret_cast<const float2*>(&noise[(size_t)(sn * NREG + i2) * 2]);
            stim_i  = (i2 == 0) ? stimulus[s / 10] : 0.f;
        } else {
            if (s > 0) xb = hist[((s & 255) << 7) + i3];   // r(s), written at iter s-1
        }
        __syncthreads();

        // ---------- phase B ----------
        if (wid >= 10) {
            if (s > 0) bstep(xb);
        } else if (wid >= 8) {
            const float c_next = cbuf[i2];

            const float dw_r = DWS * nz.x;
            const float dw_V = DWS * nz.y;

            const float I1  = g0 * c_cur + stim_i;
            const float dr1 = ONE_PI + (2.0f * xr) * xV;
            const float p1  = PI_F * xr;
            const float dV1 = ((xV * xV + eta) + 15.0f * xr + I1) - p1 * p1;

            const float xir = fmaxf((xr + 0.1f * dr1) + dw_r, 0.f);
            const float xiV = (xV + 0.1f * dV1) + dw_V;

            const float I2  = g0 * c_next + stim_i;
            const float dr2 = ONE_PI + (2.0f * xir) * xiV;
            const float p2  = PI_F * xir;
            const float dV2 = ((xiV * xiV + eta) + 15.0f * xir + I2) - p2 * p2;

            const float nxr = fmaxf((xr + 0.05f * (dr1 + dr2)) + dw_r, 0.f);
            const float nxV = (xV + 0.05f * (dV1 + dV2)) + dw_V;

            hist[(((s + 1) & 255) << 7) + i2] = nxr;       // ring slot s+1
            *reinterpret_cast<float2*>(&out[(size_t)(s * NREG + i2) * 2]) =
                make_float2(nxr, nxV);

            c_cur = c_next;
            xr = nxr;
            xV = nxV;
            nz = nz_next;
        }
        __syncthreads();
    }

    // ---- epilogue: last BOLD input r(1000), then bold output ----
    if (wid >= 10) {
        const float x = hist[((NSTEP & 255) << 7) + i3];
        bstep(x);
        const float bold = 4.0f * (K1 * (1.f - bq) + K2 * (1.f - bq * frcp_raw(bv))
                                   + 0.5f * (1.f - bv));
        out[(size_t)NSTEP * NREG * 2 + i3] = bold;
    }
}

extern "C" void kernel_launch(void* const* d_in, const int* in_sizes, int n_in,
                              void* d_out, int out_size, void* d_ws, size_t ws_size,
                              hipStream_t stream) {
    const float* region_pars  = (const float*)d_in[0];
    const float* Wt           = (const float*)d_in[1];
    const float* g            = (const float*)d_in[2];
    const float* stimulus     = (const float*)d_in[3];
    const float* noise        = (const float*)d_in[4];
    const float* initial_cond = (const float*)d_in[5];
    const int*   lags         = (const int*)d_in[6];
    // d_in[7] = ix_lag_from: always tile(arange(N)) -> implicit in our layout

    tvb_kernel<<<dim3(1), dim3(768), 0, stream>>>(
        region_pars, Wt, g, stimulus, noise, initial_cond, lags, (float*)d_out);
}